// Round 5
// baseline (212.929 us; speedup 1.0000x reference)
//
#include <hip/hip_runtime.h>
#include <hip/hip_bf16.h>

#define HH    48
#define WW    64
#define CC    256
#define ND    21
#define OUTD  441
#define PITCH 264        // LDS row pitch in bf16 elems (16B-aligned rows)
#define SROWS 32         // j' rows per parity

typedef __bf16 v8bf16 __attribute__((ext_vector_type(8)));
typedef float  v4f    __attribute__((ext_vector_type(4)));

// out[b,h,w, tj*21+ti] = (1/256) * sum_c A[b,h,w,c] * Bpad[b, h+2tj-20, w+2ti-20, c]
// Block owns (b, w-parity p, h-triple {h0,h0+2,h0+4}, hb-half ih). A fragments in
// registers (1 h-row per wave-pair, loaded once); loop over its half of the shared
// hb rows; B[hb] parity-p cols staged to LDS double-buffered. Prefetch is issued
// AFTER the barrier so the barrier's vmcnt(0) drain never exposes fresh-load latency.
__global__ __launch_bounds__(384)
void corr_mfma_kernel(const float* __restrict__ A, const float* __restrict__ B,
                      float* __restrict__ out) {
    __shared__ __bf16 Blds[2][SROWS * PITCH];   // 2 x 16,896 B

    const int blk  = blockIdx.x;
    const int b    = blk >> 6;         // 16 images
    const int rem  = (blk >> 1) & 31;  // 32 (p,hpar,trip) combos/image
    const int ih   = blk & 1;          // hb-half
    const int p    = rem & 1;          // w parity
    const int hpar = (rem >> 1) & 1;   // h parity
    const int trip = rem >> 2;         // [0,8)
    const int h0   = 6 * trip + hpar;  // rows h0, h0+2, h0+4

    const int tid  = threadIdx.x;
    const int lane = tid & 63;
    const int wave = tid >> 6;         // [0,6)
    const int mt   = wave & 1;         // w'-tile
    const int hr   = wave >> 1;        // [0,3): which h-row
    const int n    = lane & 15;
    const int quad = lane >> 4;

    const int h = h0 + 2 * hr;

    // full hb range: hb = h0 - 20 + 2i, i in [i_lo, i_hi]
    const int i_lo = (h0 >= 21) ? 0 : ((21 - h0) >> 1);
    const int i_hi = min(22, (67 - h0) >> 1);
    const int im   = (i_lo + i_hi + 1) >> 1;          // split point
    const int iA   = ih ? im : i_lo;
    const int iB   = ih ? i_hi : (im - 1);

    // ---- zero-fill invalid-tj entries (half 0 only; full-range bounds) ----
    if (ih == 0) {
        for (int r = 0; r < 3; ++r) {
            int hrow  = h0 + 2 * r;
            int tv_lo = max(0, i_lo - r);
            int tv_hi = min(20, i_hi - r);
            float* outr = out + (size_t)(b * HH + hrow) * WW * OUTD;
            for (int tj = 0; tj < ND; ++tj) {
                if (tj >= tv_lo && tj <= tv_hi) continue;
                for (int idx = tid; idx < 32 * ND; idx += 384) {
                    int wp = idx / ND, ti = idx - wp * ND;
                    int w  = (wp << 1) + p;
                    outr[(size_t)w * OUTD + tj * ND + ti] = 0.f;
                }
            }
        }
    }
    if (iA > iB) return;   // defensive (ranges are >=12 so both halves non-empty)

    // ---- A fragments (loop-invariant, loaded once) ----
    v8bf16 afrag[8];
    {
        int w_a = ((mt * 16 + n) << 1) + p;
        const float* arow = A + ((size_t)(b * HH + h) * WW + w_a) * CC;
        #pragma unroll
        for (int kc = 0; kc < 8; ++kc) {
            int c0 = kc * 32 + quad * 8;
            float4 f0 = *(const float4*)(arow + c0);
            float4 f1 = *(const float4*)(arow + c0 + 4);
            v8bf16 af;
            af[0] = (__bf16)f0.x; af[1] = (__bf16)f0.y; af[2] = (__bf16)f0.z; af[3] = (__bf16)f0.w;
            af[4] = (__bf16)f1.x; af[5] = (__bf16)f1.y; af[6] = (__bf16)f1.z; af[7] = (__bf16)f1.w;
            afrag[kc] = af;
        }
    }

    // ---- staging helpers: 32 j'-rows x 64 float4-chunks = 2048 chunks / 384 thr ----
    const float* bimg = B + (size_t)(b * HH) * WW * CC + p * CC;  // +p: j = 2j'+p
    float4 pf[6];
    auto load_pf = [&](int hb) {
        const float* brow = bimg + (size_t)hb * WW * CC;
        #pragma unroll
        for (int it = 0; it < 6; ++it) {
            int idx = it * 384 + tid;
            if (idx < 2048)
                pf[it] = *(const float4*)(brow + (idx >> 6) * 2 * CC + ((idx & 63) << 2));
        }
    };
    auto store_lds = [&](int buf) {
        #pragma unroll
        for (int it = 0; it < 6; ++it) {
            int idx = it * 384 + tid;
            if (idx < 2048) {
                __bf16* dst = &Blds[buf][(idx >> 6) * PITCH + ((idx & 63) << 2)];
                dst[0] = (__bf16)pf[it].x; dst[1] = (__bf16)pf[it].y;
                dst[2] = (__bf16)pf[it].z; dst[3] = (__bf16)pf[it].w;
            }
        }
    };

    load_pf(h0 - 20 + 2 * iA);
    store_lds(0);
    int cur = 0;

    float* outr = out + (size_t)(b * HH + h) * WW * OUTD;

    for (int i = iA; i <= iB; ++i) {
        __syncthreads();                 // buf[cur] ready; prior readers of buf[cur^1] done
        if (i < iB) load_pf(h0 - 20 + 2 * (i + 1));   // issue AFTER barrier -> latency hidden

        const int tj = i - hr;
        if ((unsigned)tj <= 20u) {
            const __bf16* bbase = &Blds[cur][n * PITCH + quad * 8];
            v4f acc0 = {0.f, 0.f, 0.f, 0.f};
            v4f acc1 = acc0;
            #pragma unroll
            for (int kc = 0; kc < 8; ++kc) {
                v8bf16 bf0 = *(const v8bf16*)(bbase + kc * 32);                // j' = n
                v8bf16 bf1 = *(const v8bf16*)(bbase + 16 * PITCH + kc * 32);   // j' = 16+n
                acc0 = __builtin_amdgcn_mfma_f32_16x16x32_bf16(afrag[kc], bf0, acc0, 0, 0, 0);
                acc1 = __builtin_amdgcn_mfma_f32_16x16x32_bf16(afrag[kc], bf1, acc1, 0, 0, 0);
            }
            // epilogue: D col = n (-> j'), row = quad*4 + r (-> w' within tile)
            #pragma unroll
            for (int r = 0; r < 4; ++r) {
                int wp = mt * 16 + quad * 4 + r;
                int w  = (wp << 1) + p;
                float* orow = outr + (size_t)w * OUTD + tj * ND;
                int ti0 = 10 + n - wp;
                if ((unsigned)ti0 < 21u) orow[ti0] = acc0[r] * (1.f / 256.f);
                int ti1 = 26 + n - wp;
                if ((unsigned)ti1 < 21u) orow[ti1] = acc1[r] * (1.f / 256.f);
                // out-of-image j => exact zeros
                if (n < 10 - wp)  orow[n]      = 0.f;
                if (n <= wp - 22) orow[20 - n] = 0.f;
            }
        }

        if (i < iB) store_lds(cur ^ 1);  // consume pf into the other buffer
        cur ^= 1;
    }
}

extern "C" void kernel_launch(void* const* d_in, const int* in_sizes, int n_in,
                              void* d_out, int out_size, void* d_ws, size_t ws_size,
                              hipStream_t stream) {
    const float* A = (const float*)d_in[0];
    const float* B = (const float*)d_in[1];
    float* out = (float*)d_out;
    dim3 grid(16 * 64);
    dim3 block(384);
    corr_mfma_kernel<<<grid, block, 0, stream>>>(A, B, out);
}